// Round 8
// baseline (381.394 us; speedup 1.0000x reference)
//
#include <hip/hip_runtime.h>

typedef unsigned short u16;
typedef __attribute__((ext_vector_type(8))) short bf16x8;
typedef __attribute__((ext_vector_type(4))) float f32x4;
typedef __attribute__((ext_vector_type(16))) float f32x16;

__device__ __forceinline__ u16 f2bf(float f) {
  union { float f; unsigned u; } x; x.f = f;
  return (u16)((x.u + 0x7FFFu + ((x.u >> 16) & 1u)) >> 16);
}
__device__ __forceinline__ float bf2f(u16 h) {
  union { unsigned u; float f; } x; x.u = ((unsigned)h) << 16; return x.f;
}
// packed RNE f32x2 -> bf16x2 (hardware, single VALU op)
__device__ __forceinline__ unsigned cvtpk(float lo, float hi) {
  unsigned r;
  asm("v_cvt_pk_bf16_f32 %0, %1, %2" : "=v"(r) : "v"(lo), "v"(hi));
  return r;
}
// barrier WITHOUT vmcnt drain: ds-ops flushed (lgkmcnt 0), global loads stay in flight.
// sched_barrier fences per rule #18 (compiler may hoist reg-only ops past inline-asm waits).
__device__ __forceinline__ void bar_ds() {
  asm volatile("s_waitcnt lgkmcnt(0)" ::: "memory");
  __builtin_amdgcn_sched_barrier(0);
  __builtin_amdgcn_s_barrier();
  __builtin_amdgcn_sched_barrier(0);
}

// Weight frag layout (bf16):
//  L0..L2 (32x32x16 frags): per (mt, ks): 64 lanes x 8 bf16 = 512 u16.
//    lane l -> row = mt*32 + (l&31), k = ks*16 + (l>>5)*8 + j
//  L3 (16x16x32 frags): lane l -> row = mt*16 + (l&15), k = ks*32 + (l>>4)*8 + j
// Offsets (u16 elems): L0 @0 (16mt x 40ks), L1 @327680 (8 x 32), L2 @458752 (4 x 16), L3 @491520 (4 x 4)

__global__ __launch_bounds__(256) void prep_kernel(
    const float* __restrict__ W0, const float* __restrict__ W1,
    const float* __restrict__ W2, const float* __restrict__ W3,
    const float* __restrict__ b0, const float* __restrict__ g0, const float* __restrict__ be0, const float* __restrict__ m0, const float* __restrict__ v0,
    const float* __restrict__ b1, const float* __restrict__ g1, const float* __restrict__ be1, const float* __restrict__ m1, const float* __restrict__ v1,
    const float* __restrict__ b2, const float* __restrict__ g2, const float* __restrict__ be2, const float* __restrict__ m2, const float* __restrict__ v2,
    const float* __restrict__ b3, const float* __restrict__ g3, const float* __restrict__ be3, const float* __restrict__ m3, const float* __restrict__ v3,
    u16* __restrict__ Wb, float* __restrict__ sc, float* __restrict__ sh)
{
  int i = blockIdx.x * 256 + threadIdx.x;
  if (i < 62464) {
    const float* Ws; int CIN, KS, local, dstb; bool f16 = false;
    if (i < 40960)      { local = i;         Ws = W0; CIN = 640; KS = 40; dstb = 0; }
    else if (i < 57344) { local = i - 40960; Ws = W1; CIN = 512; KS = 32; dstb = 327680; }
    else if (i < 61440) { local = i - 57344; Ws = W2; CIN = 256; KS = 16; dstb = 458752; }
    else                { local = i - 61440; Ws = W3; CIN = 128; KS = 4;  dstb = 491520; f16 = true; }
    int lane = local & 63, fi = local >> 6;
    int ks = fi % KS, mt = fi / KS;
    int row, k;
    if (!f16) { row = mt * 32 + (lane & 31); k = ks * 16 + (lane >> 5) * 8; }
    else      { row = mt * 16 + (lane & 15); k = ks * 32 + (lane >> 4) * 8; }
    const float* s = Ws + (size_t)row * CIN + k;
    bf16x8 pk;
    #pragma unroll
    for (int j = 0; j < 8; ++j) pk[j] = (short)f2bf(s[j]);
    *reinterpret_cast<bf16x8*>(Wb + dstb + (size_t)local * 8) = pk;
  }
  if (i < 960) {
    const float *B, *G, *BE, *M, *V; int c;
    if (i < 512)      { c = i;       B = b0; G = g0; BE = be0; M = m0; V = v0; }
    else if (i < 768) { c = i - 512; B = b1; G = g1; BE = be1; M = m1; V = v1; }
    else if (i < 896) { c = i - 768; B = b2; G = g2; BE = be2; M = m2; V = v2; }
    else              { c = i - 896; B = b3; G = g3; BE = be3; M = m3; V = v3; }
    float inv = G[c] / sqrtf(V[c] + 1e-5f);
    sc[i] = inv;
    sh[i] = (B[c] - M[c]) * inv + BE[c];
  }
}

// store helper for 32x32 acc tiles -> bf16 LDS tile [px][ch], stride rowB bytes,
// swizzle byte ^= (px&7)<<4.  C/D: col(px)=l&31, row(ch)= (r&3) + 8*(r>>2) + 4*(l>>5)
template<int MT, int NT>
__device__ __forceinline__ void store_act32(f32x16 (&acc)[MT][NT],
    const float* __restrict__ sc, const float* __restrict__ sh,
    int mrow0, int ntb, int lane, u16* __restrict__ dst, int rowB)
{
  const int l31 = lane & 31, khalf = lane >> 5;
  #pragma unroll
  for (int mi = 0; mi < MT; ++mi) {
    #pragma unroll
    for (int rq = 0; rq < 4; ++rq) {
      const int ch0 = mrow0 + mi * 32 + rq * 8 + khalf * 4;
      const f32x4 s4 = *reinterpret_cast<const f32x4*>(sc + ch0);
      const f32x4 h4 = *reinterpret_cast<const f32x4*>(sh + ch0);
      #pragma unroll
      for (int nt = 0; nt < NT; ++nt) {
        const int px = (ntb + nt) * 32 + l31;
        float r0 = fmaxf(acc[mi][nt][rq * 4 + 0] * s4[0] + h4[0], 0.f);
        float r1 = fmaxf(acc[mi][nt][rq * 4 + 1] * s4[1] + h4[1], 0.f);
        float r2 = fmaxf(acc[mi][nt][rq * 4 + 2] * s4[2] + h4[2], 0.f);
        float r3 = fmaxf(acc[mi][nt][rq * 4 + 3] * s4[3] + h4[3], 0.f);
        uint2 pk;
        pk.x = cvtpk(r0, r1);
        pk.y = cvtpk(r2, r3);
        const unsigned byte = ((unsigned)(px * rowB + ch0 * 2)) ^ ((unsigned)((px & 7) << 4));
        *reinterpret_cast<uint2*>(reinterpret_cast<char*>(dst) + byte) = pk;
      }
    }
  }
}

// staging: thread owns px=lane; 8 channels at choff..choff+7
__device__ __forceinline__ void load8(const float* __restrict__ gbase, int choff, float (&v)[8]) {
  const float* s = gbase + (size_t)choff * 32768u;
  #pragma unroll
  for (int kk = 0; kk < 8; ++kk) v[kk] = s[(size_t)kk * 32768u];
}
__device__ __forceinline__ void write8(float (&v)[8], char* __restrict__ buf, unsigned wb) {
  uint4 pk;
  pk.x = cvtpk(v[0], v[1]);
  pk.y = cvtpk(v[2], v[3]);
  pk.z = cvtpk(v[4], v[5]);
  pk.w = cvtpk(v[6], v[7]);
  *reinterpret_cast<uint4*>(buf + wb) = pk;
}

// half-chunk of phase0 MFMA: 4 k-steps (ks0..ks0+3) of a 128-ch chunk, acc[2][2].
// X tile: [64px][128ch] stride 256B, swizzle ^((px&7)<<4). Continuous A-ring depth 2.
#define P0_HALF(XB, c, ks0) { \
  __builtin_amdgcn_s_setprio(1); \
  _Pragma("unroll") \
  for (int ksl = 0; ksl < 4; ++ksl) { \
    const int ks = (ks0) + ksl; \
    const unsigned base = ((unsigned)(l31 * 256 + ks * 32 + khalf * 16)) ^ sw; \
    bf16x8 bb0 = *reinterpret_cast<const bf16x8*>((XB) + base); \
    bf16x8 bb1 = *reinterpret_cast<const bf16x8*>((XB) + base + 8192); \
    const int slot = ks & 1; \
    acc0[0][0] = __builtin_amdgcn_mfma_f32_32x32x16_bf16(ar0[slot], bb0, acc0[0][0], 0, 0, 0); \
    acc0[0][1] = __builtin_amdgcn_mfma_f32_32x32x16_bf16(ar0[slot], bb1, acc0[0][1], 0, 0, 0); \
    acc0[1][0] = __builtin_amdgcn_mfma_f32_32x32x16_bf16(ar1[slot], bb0, acc0[1][0], 0, 0, 0); \
    acc0[1][1] = __builtin_amdgcn_mfma_f32_32x32x16_bf16(ar1[slot], bb1, acc0[1][1], 0, 0, 0); \
    const int g_ = (c) * 8 + ks + 2; \
    if (g_ < 40) { \
      ar0[slot] = *reinterpret_cast<const bf16x8*>(A0 + g_ * 512); \
      ar1[slot] = *reinterpret_cast<const bf16x8*>(A1 + g_ * 512); \
    } \
  } \
  __builtin_amdgcn_s_setprio(0); \
}

// LDS map (64 KB total, 2 blocks/CU):
//   phase0: XsA [0,16K) = [64px][128ch] swz; XsB [16K,32K)  (double buffer)
//   Y0 [0,64K) stride 1024B  -- overlays X buffers AFTER the final phase0 barrier
//   Y1 [0,32K) stride 512B   -- overlays Y0 after barrier
//   Y2 [32K,48K) stride 256B
__global__ __launch_bounds__(512, 4) void fused4_kernel(
    const float* __restrict__ gp, const u16* __restrict__ Wb,
    const float* __restrict__ sc, const float* __restrict__ sh,
    u16* __restrict__ x3)
{
  __shared__ u16 smem[32768];   // 64 KB
  char* XsA = reinterpret_cast<char*>(smem);
  char* XsB = XsA + 16384;
  u16*  Y0s = smem;

  const int tid  = threadIdx.x;
  const int lane = tid & 63;
  const int w    = tid >> 6;
  const int l31  = lane & 31, khalf = lane >> 5;
  const unsigned sw = (unsigned)((l31 & 7) << 4);

  const int b  = blockIdx.x >> 9;
  const int jt = blockIdx.x & 511;
  const int j0 = jt << 6;

  // staging: thread px = lane; chunk c half h covers ch = c*128 + h*64 + w*8 .. +7
  const float* gbase = gp + (size_t)b * (640u * 32768u) + (unsigned)(j0 + lane);
  const unsigned wbH0 = ((unsigned)(lane * 256 + w * 16)) ^ ((unsigned)((lane & 7) << 4));
  const unsigned wbH1 = wbH0 + 128;   // h*64ch*2B; swizzle bits (4..6) unaffected by +128

  const u16* A0 = Wb + (size_t)(2 * w) * (40 * 512) + lane * 8;
  const u16* A1 = A0 + (size_t)(40 * 512);

  float vA[8], vB[8];
  bf16x8 ar0[2], ar1[2];
  f32x16 acc0[2][2] = {};

  // ---- phase 0 prologue: chunk 0 -> XsA; A-ring frags 0,1
  load8(gbase, 0 * 128 + 0 * 64 + w * 8, vA);
  load8(gbase, 0 * 128 + 1 * 64 + w * 8, vB);
  ar0[0] = *reinterpret_cast<const bf16x8*>(A0 + 0 * 512);
  ar1[0] = *reinterpret_cast<const bf16x8*>(A1 + 0 * 512);
  ar0[1] = *reinterpret_cast<const bf16x8*>(A0 + 1 * 512);
  ar1[1] = *reinterpret_cast<const bf16x8*>(A1 + 1 * 512);
  write8(vA, XsA, wbH0);
  write8(vB, XsA, wbH1);
  bar_ds();

  // ---- phase 0 main: 5 chunks of 128 ch, LDS dbuf, 1 no-drain barrier/chunk
  #pragma unroll 1
  for (int c = 0; c < 5; ++c) {
    char* bufc = (c & 1) ? XsB : XsA;
    char* bufn = (c & 1) ? XsA : XsB;
    if (c < 4) {
      load8(gbase, (c + 1) * 128 + 0 * 64 + w * 8, vA);
      load8(gbase, (c + 1) * 128 + 1 * 64 + w * 8, vB);
    }
    P0_HALF(bufc, c, 0);
    if (c < 4) write8(vA, bufn, wbH0);
    P0_HALF(bufc, c, 4);
    if (c < 4) write8(vB, bufn, wbH1);
    bar_ds();
  }

  // Y0 store overlays X buffers (barrier above guarantees all reads done)
  store_act32<2, 2>(acc0, sc, sh, w * 64, 0, lane, Y0s, 1024);
  bar_ds();

  // ---- phase 1: 512 -> 256  (wave w: m-tiles (w&3)*2,(w&3)*2+1; n-tile w>>2)
  //      (m2,n1): halves LDS B-reads vs (m1,n2); A prefetch via continuous ring depth 2
  {
    f32x16 acc1[2][1] = {};
    const u16* B0 = Wb + 327680 + (size_t)((w & 3) * 2) * (32 * 512) + lane * 8;
    const u16* B1 = B0 + 32 * 512;
    const int pxb = (w >> 2) * 32;
    bf16x8 br0[2], br1[2];
    br0[0] = *reinterpret_cast<const bf16x8*>(B0 + 0 * 512);
    br1[0] = *reinterpret_cast<const bf16x8*>(B1 + 0 * 512);
    br0[1] = *reinterpret_cast<const bf16x8*>(B0 + 1 * 512);
    br1[1] = *reinterpret_cast<const bf16x8*>(B1 + 1 * 512);
    __builtin_amdgcn_s_setprio(1);
    #pragma unroll
    for (int ks = 0; ks < 32; ++ks) {
      const unsigned kb = (unsigned)(ks * 32 + khalf * 16);
      bf16x8 bb = *reinterpret_cast<const bf16x8*>(reinterpret_cast<const char*>(Y0s) + (((unsigned)((pxb + l31) * 1024) + kb) ^ sw));
      const int slot = ks & 1;
      acc1[0][0] = __builtin_amdgcn_mfma_f32_32x32x16_bf16(br0[slot], bb, acc1[0][0], 0, 0, 0);
      acc1[1][0] = __builtin_amdgcn_mfma_f32_32x32x16_bf16(br1[slot], bb, acc1[1][0], 0, 0, 0);
      if (ks < 30) {
        br0[slot] = *reinterpret_cast<const bf16x8*>(B0 + (ks + 2) * 512);
        br1[slot] = *reinterpret_cast<const bf16x8*>(B1 + (ks + 2) * 512);
      }
    }
    __builtin_amdgcn_s_setprio(0);
    bar_ds();   // all waves done reading Y0
    store_act32<2, 1>(acc1, sc + 512, sh + 512, (w & 3) * 64, w >> 2, lane, Y0s, 512);  // Y1 overlays Y0
    bar_ds();
  }

  // ---- phase 2: 256 -> 128  (wave w: mt=w&3 rows, nt=w>>2 32-px tile), ring depth 8
  {
    f32x16 acc2[1][1] = {};
    const u16* A = Wb + 458752 + (size_t)(w & 3) * (16 * 512) + lane * 8;
    const int pxb = (w >> 2) * 32;
    bf16x8 ar8[8];
    #pragma unroll
    for (int q = 0; q < 8; ++q) ar8[q] = *reinterpret_cast<const bf16x8*>(A + q * 512);
    __builtin_amdgcn_s_setprio(1);
    #pragma unroll
    for (int ks = 0; ks < 16; ++ks) {
      const unsigned kb = (unsigned)(ks * 32 + khalf * 16);
      bf16x8 bb0 = *reinterpret_cast<const bf16x8*>(reinterpret_cast<const char*>(Y0s) + (((unsigned)((pxb + l31) * 512) + kb) ^ sw));
      acc2[0][0] = __builtin_amdgcn_mfma_f32_32x32x16_bf16(ar8[ks & 7], bb0, acc2[0][0], 0, 0, 0);
      if (ks < 8) ar8[ks & 7] = *reinterpret_cast<const bf16x8*>(A + (ks + 8) * 512);
    }
    __builtin_amdgcn_s_setprio(0);
    // Y2 -> [32K,48K) (disjoint from Y1 reads in [0,32K))
    store_act32<1, 1>(acc2, sc + 768, sh + 768, (w & 3) * 32, w >> 2, lane, smem + 16384, 256);
    bar_ds();
  }

  // ---- phase 3: 128 -> 64  (16x16x32; wave w: mt=w&3, n-tiles 2*(w>>2)+{0,1})
  {
    const int r16 = lane & 15, g = lane >> 4;
    f32x4 acc3[2] = {};
    const u16* A = Wb + 491520 + (size_t)(w & 3) * (4 * 512) + lane * 8;
    bf16x8 a4[4];
    #pragma unroll
    for (int q = 0; q < 4; ++q) a4[q] = *reinterpret_cast<const bf16x8*>(A + q * 512);
    const int ntb = (w >> 2) * 2;
    __builtin_amdgcn_s_setprio(1);
    #pragma unroll
    for (int ks = 0; ks < 4; ++ks) {
      #pragma unroll
      for (int nt = 0; nt < 2; ++nt) {
        const int px = (ntb + nt) * 16 + r16;
        const unsigned byte = ((unsigned)(px * 256 + ks * 64 + g * 16)) ^ ((unsigned)((px & 7) << 4));
        bf16x8 bb = *reinterpret_cast<const bf16x8*>(reinterpret_cast<const char*>(smem) + 32768 + byte);
        acc3[nt] = __builtin_amdgcn_mfma_f32_16x16x32_bf16(a4[ks], bb, acc3[nt], 0, 0, 0);
      }
    }
    __builtin_amdgcn_s_setprio(0);
    const int c0 = (w & 3) * 16 + g * 4;
    const f32x4 s4 = *reinterpret_cast<const f32x4*>(sc + 896 + c0);
    const f32x4 h4 = *reinterpret_cast<const f32x4*>(sh + 896 + c0);
    u16* x3b = x3 + ((size_t)b << 21) + j0;
    #pragma unroll
    for (int nt = 0; nt < 2; ++nt) {
      const int n = (ntb + nt) * 16 + r16;
      #pragma unroll
      for (int r = 0; r < 4; ++r) {
        float vv = fmaxf(acc3[nt][r] * s4[r] + h4[r], 0.f);
        x3b[(size_t)(c0 + r) * 32768 + n] = f2bf(vv);
      }
    }
  }
}

// ---------------- softmax over K + weighted sum with xyz (2 s per thread) ----------------
__global__ __launch_bounds__(256) void softmax_ws_kernel(
    const u16* __restrict__ x3, const float* __restrict__ xyz,
    float* __restrict__ out)
{
  const int tid = blockIdx.x * 256 + threadIdx.x;   // 0 .. 262143
  const int b = tid >> 15;
  const int rem = tid & 32767;
  const int d = rem >> 9;
  const int s0 = (rem & 511) * 2;

  const u16* xp = x3 + ((size_t)(b * 64 + d) << 15) + s0;
  float pa[32], pb[32];
  float mxa = -1e30f, mxb = -1e30f;
  #pragma unroll
  for (int k = 0; k < 32; ++k) {
    const unsigned u = *reinterpret_cast<const unsigned*>(xp + ((size_t)k << 10));
    const float va = bf2f((u16)(u & 0xFFFFu));
    const float vb = bf2f((u16)(u >> 16));
    pa[k] = va; pb[k] = vb;
    mxa = fmaxf(mxa, va); mxb = fmaxf(mxb, vb);
  }
  float sa = 0.f, sb = 0.f;
  #pragma unroll
  for (int k = 0; k < 32; ++k) {
    pa[k] = __expf(pa[k] - mxa); sa += pa[k];
    pb[k] = __expf(pb[k] - mxb); sb += pb[k];
  }
  const float inva = 1.0f / sa, invb = 1.0f / sb;

  const float* zp = xyz + (size_t)b * (3 * 32768) + s0;
  #pragma unroll
  for (int c = 0; c < 3; ++c) {
    float ax = 0.f, ay = 0.f;
    #pragma unroll
    for (int k = 0; k < 32; ++k) {
      const float2 z = *reinterpret_cast<const float2*>(zp + c * 32768 + (k << 10));
      ax += pa[k] * z.x; ay += pb[k] * z.y;
    }
    float2 o; o.x = ax * inva; o.y = ay * invb;
    *reinterpret_cast<float2*>(out + ((size_t)((b * 3 + c) * 64 + d) << 10) + s0) = o;
  }
}

// ---------------- launcher ----------------
extern "C" void kernel_launch(void* const* d_in, const int* in_sizes, int n_in,
                              void* d_out, int out_size, void* d_ws, size_t ws_size,
                              hipStream_t stream) {
  const float* xyz = (const float*)d_in[0];
  const float* gp  = (const float*)d_in[1];
  const float* W0 = (const float*)d_in[2];
  const float* W1 = (const float*)d_in[8];
  const float* W2 = (const float*)d_in[14];
  const float* W3 = (const float*)d_in[20];

  char* ws = (char*)d_ws;
  u16*   Wb = (u16*)ws;                       // 499712 bf16 -> 999424 B
  float* sc = (float*)(ws + 999424);          // 960 f32
  float* sh = (float*)(ws + 1003264);         // 960 f32
  u16*   x3 = (u16*)(ws + 1007104);           // 8*64*32768 bf16 = 33.5 MB

  prep_kernel<<<245, 256, 0, stream>>>(
      W0, W1, W2, W3,
      (const float*)d_in[3],  (const float*)d_in[4],  (const float*)d_in[5],  (const float*)d_in[6],  (const float*)d_in[7],
      (const float*)d_in[9],  (const float*)d_in[10], (const float*)d_in[11], (const float*)d_in[12], (const float*)d_in[13],
      (const float*)d_in[15], (const float*)d_in[16], (const float*)d_in[17], (const float*)d_in[18], (const float*)d_in[19],
      (const float*)d_in[21], (const float*)d_in[22], (const float*)d_in[23], (const float*)d_in[24], (const float*)d_in[25],
      Wb, sc, sh);

  fused4_kernel<<<4096, 512, 0, stream>>>(gp, Wb, sc, sh, x3);

  softmax_ws_kernel<<<1024, 256, 0, stream>>>(x3, xyz, (float*)d_out);
}

// Round 9
// 360.141 us; speedup vs baseline: 1.0590x; 1.0590x over previous
//
#include <hip/hip_runtime.h>

typedef unsigned short u16;
typedef __attribute__((ext_vector_type(8))) short bf16x8;
typedef __attribute__((ext_vector_type(4))) float f32x4;
typedef __attribute__((ext_vector_type(16))) float f32x16;

__device__ __forceinline__ u16 f2bf(float f) {
  union { float f; unsigned u; } x; x.f = f;
  return (u16)((x.u + 0x7FFFu + ((x.u >> 16) & 1u)) >> 16);
}
__device__ __forceinline__ float bf2f(u16 h) {
  union { unsigned u; float f; } x; x.u = ((unsigned)h) << 16; return x.f;
}
// packed RNE f32x2 -> bf16x2 (hardware, single VALU op)
__device__ __forceinline__ unsigned cvtpk(float lo, float hi) {
  unsigned r;
  asm("v_cvt_pk_bf16_f32 %0, %1, %2" : "=v"(r) : "v"(lo), "v"(hi));
  return r;
}

// Weight frag layout (bf16):
//  L0..L2 (32x32x16 frags): per (mt, ks): 64 lanes x 8 bf16 = 512 u16.
//    lane l -> row = mt*32 + (l&31), k = ks*16 + (l>>5)*8 + j
//  L3 (16x16x32 frags): lane l -> row = mt*16 + (l&15), k = ks*32 + (l>>4)*8 + j
// Offsets (u16 elems): L0 @0 (16mt x 40ks), L1 @327680 (8 x 32), L2 @458752 (4 x 16), L3 @491520 (4 x 4)

__global__ __launch_bounds__(256) void prep_kernel(
    const float* __restrict__ W0, const float* __restrict__ W1,
    const float* __restrict__ W2, const float* __restrict__ W3,
    const float* __restrict__ b0, const float* __restrict__ g0, const float* __restrict__ be0, const float* __restrict__ m0, const float* __restrict__ v0,
    const float* __restrict__ b1, const float* __restrict__ g1, const float* __restrict__ be1, const float* __restrict__ m1, const float* __restrict__ v1,
    const float* __restrict__ b2, const float* __restrict__ g2, const float* __restrict__ be2, const float* __restrict__ m2, const float* __restrict__ v2,
    const float* __restrict__ b3, const float* __restrict__ g3, const float* __restrict__ be3, const float* __restrict__ m3, const float* __restrict__ v3,
    u16* __restrict__ Wb, float* __restrict__ sc, float* __restrict__ sh)
{
  int i = blockIdx.x * 256 + threadIdx.x;
  if (i < 62464) {
    const float* Ws; int CIN, KS, local, dstb; bool f16 = false;
    if (i < 40960)      { local = i;         Ws = W0; CIN = 640; KS = 40; dstb = 0; }
    else if (i < 57344) { local = i - 40960; Ws = W1; CIN = 512; KS = 32; dstb = 327680; }
    else if (i < 61440) { local = i - 57344; Ws = W2; CIN = 256; KS = 16; dstb = 458752; }
    else                { local = i - 61440; Ws = W3; CIN = 128; KS = 4;  dstb = 491520; f16 = true; }
    int lane = local & 63, fi = local >> 6;
    int ks = fi % KS, mt = fi / KS;
    int row, k;
    if (!f16) { row = mt * 32 + (lane & 31); k = ks * 16 + (lane >> 5) * 8; }
    else      { row = mt * 16 + (lane & 15); k = ks * 32 + (lane >> 4) * 8; }
    const float* s = Ws + (size_t)row * CIN + k;
    bf16x8 pk;
    #pragma unroll
    for (int j = 0; j < 8; ++j) pk[j] = (short)f2bf(s[j]);
    *reinterpret_cast<bf16x8*>(Wb + dstb + (size_t)local * 8) = pk;
  }
  if (i < 960) {
    const float *B, *G, *BE, *M, *V; int c;
    if (i < 512)      { c = i;       B = b0; G = g0; BE = be0; M = m0; V = v0; }
    else if (i < 768) { c = i - 512; B = b1; G = g1; BE = be1; M = m1; V = v1; }
    else if (i < 896) { c = i - 768; B = b2; G = g2; BE = be2; M = m2; V = v2; }
    else              { c = i - 896; B = b3; G = g3; BE = be3; M = m3; V = v3; }
    float inv = G[c] / sqrtf(V[c] + 1e-5f);
    sc[i] = inv;
    sh[i] = (B[c] - M[c]) * inv + BE[c];
  }
}

// store helper for 32x32 acc tiles -> bf16 LDS tile [px][ch], stride rowB bytes,
// swizzle byte ^= (px&7)<<4.  C/D: col(px)=l&31, row(ch)= (r&3) + 8*(r>>2) + 4*(l>>5)
template<int MT, int NT>
__device__ __forceinline__ void store_act32(f32x16 (&acc)[MT][NT],
    const float* __restrict__ sc, const float* __restrict__ sh,
    int mrow0, int ntb, int lane, u16* __restrict__ dst, int rowB)
{
  const int l31 = lane & 31, khalf = lane >> 5;
  #pragma unroll
  for (int mi = 0; mi < MT; ++mi) {
    #pragma unroll
    for (int rq = 0; rq < 4; ++rq) {
      const int ch0 = mrow0 + mi * 32 + rq * 8 + khalf * 4;
      const f32x4 s4 = *reinterpret_cast<const f32x4*>(sc + ch0);
      const f32x4 h4 = *reinterpret_cast<const f32x4*>(sh + ch0);
      #pragma unroll
      for (int nt = 0; nt < NT; ++nt) {
        const int px = (ntb + nt) * 32 + l31;
        float r0 = fmaxf(acc[mi][nt][rq * 4 + 0] * s4[0] + h4[0], 0.f);
        float r1 = fmaxf(acc[mi][nt][rq * 4 + 1] * s4[1] + h4[1], 0.f);
        float r2 = fmaxf(acc[mi][nt][rq * 4 + 2] * s4[2] + h4[2], 0.f);
        float r3 = fmaxf(acc[mi][nt][rq * 4 + 3] * s4[3] + h4[3], 0.f);
        uint2 pk;
        pk.x = cvtpk(r0, r1);
        pk.y = cvtpk(r2, r3);
        const unsigned byte = ((unsigned)(px * rowB + ch0 * 2)) ^ ((unsigned)((px & 7) << 4));
        *reinterpret_cast<uint2*>(reinterpret_cast<char*>(dst) + byte) = pk;
      }
    }
  }
}

// half-chunk of phase0 MFMA: 4 k-steps (ks0..ks0+3) of a 128-ch chunk, acc[2][2].
// X tile: [64px][128ch] stride 256B, swizzle ^((px&7)<<4). Continuous A-ring depth 2.
#define P0_HALF(XB, c, ks0) { \
  __builtin_amdgcn_s_setprio(1); \
  _Pragma("unroll") \
  for (int ksl = 0; ksl < 4; ++ksl) { \
    const int ks = (ks0) + ksl; \
    const unsigned base = ((unsigned)(l31 * 256 + ks * 32 + khalf * 16)) ^ sw; \
    bf16x8 bb0 = *reinterpret_cast<const bf16x8*>((XB) + base); \
    bf16x8 bb1 = *reinterpret_cast<const bf16x8*>((XB) + base + 8192); \
    const int slot = ks & 1; \
    acc0[0][0] = __builtin_amdgcn_mfma_f32_32x32x16_bf16(ar0[slot], bb0, acc0[0][0], 0, 0, 0); \
    acc0[0][1] = __builtin_amdgcn_mfma_f32_32x32x16_bf16(ar0[slot], bb1, acc0[0][1], 0, 0, 0); \
    acc0[1][0] = __builtin_amdgcn_mfma_f32_32x32x16_bf16(ar1[slot], bb0, acc0[1][0], 0, 0, 0); \
    acc0[1][1] = __builtin_amdgcn_mfma_f32_32x32x16_bf16(ar1[slot], bb1, acc0[1][1], 0, 0, 0); \
    const int g_ = (c) * 8 + ks + 2; \
    if (g_ < 40) { \
      ar0[slot] = *reinterpret_cast<const bf16x8*>(A0 + g_ * 512); \
      ar1[slot] = *reinterpret_cast<const bf16x8*>(A1 + g_ * 512); \
    } \
  } \
  __builtin_amdgcn_s_setprio(0); \
}

// px-pair staging: thread owns px {2*pxq, 2*pxq+1} x 8 channels (cho*8..+7) of each 128-ch chunk.
// 8 float2 loads per chunk (half the VMEM instructions of per-px scalar staging).
#define LOADC(c) { const float* s_ = gsrc + (size_t)((c) * 128) * 32768u; \
    _Pragma("unroll") for (int kk = 0; kk < 8; ++kk) \
      vv[kk] = *reinterpret_cast<const float2*>(s_ + (size_t)kk * 32768u); }
#define WRITEPX0(BUF) { bf16x8 pk; \
    _Pragma("unroll") for (int kk = 0; kk < 8; ++kk) pk[kk] = (short)f2bf(vv[kk].x); \
    *reinterpret_cast<bf16x8*>((BUF) + wb0) = pk; }
#define WRITEPX1(BUF) { bf16x8 pk; \
    _Pragma("unroll") for (int kk = 0; kk < 8; ++kk) pk[kk] = (short)f2bf(vv[kk].y); \
    *reinterpret_cast<bf16x8*>((BUF) + wb1) = pk; }

// LDS map (64 KB total, 2 blocks/CU):
//   phase0: XsA [0,16K) = [64px][128ch] swz; XsB [16K,32K)  (double buffer)
//   Y0 [0,64K) stride 1024B  -- overlays X buffers AFTER the final phase0 barrier
//   Y1 [0,32K) stride 512B   -- overlays Y0 after barrier
//   Y2 [32K,48K) stride 256B
__global__ __launch_bounds__(512, 4) void fused4_kernel(
    const float* __restrict__ gp, const u16* __restrict__ Wb,
    const float* __restrict__ sc, const float* __restrict__ sh,
    u16* __restrict__ x3)
{
  __shared__ u16 smem[32768];   // 64 KB
  char* XsA = reinterpret_cast<char*>(smem);
  char* XsB = XsA + 16384;
  u16*  Y0s = smem;

  const int tid  = threadIdx.x;
  const int lane = tid & 63;
  const int w    = tid >> 6;
  const int l31  = lane & 31, khalf = lane >> 5;
  const unsigned sw = (unsigned)((l31 & 7) << 4);

  const int b  = blockIdx.x >> 9;
  const int jt = blockIdx.x & 511;
  const int j0 = jt << 6;

  // staging mapping: pxq = tid&31 -> px {2pxq, 2pxq+1}; cho = tid>>5 (0..15) -> ch cho*8..+7
  const int pxq = tid & 31;
  const int cho = tid >> 5;
  const float* gsrc = gp + (size_t)b * (640u * 32768u)
                         + (size_t)(cho * 8) * 32768u + (unsigned)(j0 + 2 * pxq);
  const int px0 = 2 * pxq, px1 = px0 + 1;
  const unsigned wb0 = ((unsigned)(px0 * 256 + cho * 16)) ^ ((unsigned)((px0 & 7) << 4));
  const unsigned wb1 = ((unsigned)(px1 * 256 + cho * 16)) ^ ((unsigned)((px1 & 7) << 4));

  const u16* A0 = Wb + (size_t)(2 * w) * (40 * 512) + lane * 8;
  const u16* A1 = A0 + (size_t)(40 * 512);

  float2 vv[8];
  bf16x8 ar0[2], ar1[2];
  f32x16 acc0[2][2] = {};

  // ---- phase 0 prologue: chunk 0 -> XsA; A-ring frags 0,1
  LOADC(0);
  ar0[0] = *reinterpret_cast<const bf16x8*>(A0 + 0 * 512);
  ar1[0] = *reinterpret_cast<const bf16x8*>(A1 + 0 * 512);
  ar0[1] = *reinterpret_cast<const bf16x8*>(A0 + 1 * 512);
  ar1[1] = *reinterpret_cast<const bf16x8*>(A1 + 1 * 512);
  WRITEPX0(XsA);
  WRITEPX1(XsA);
  __syncthreads();

  // ---- phase 0 main: 5 chunks of 128 ch, LDS dbuf, 1 barrier/chunk
  #pragma unroll 1
  for (int c = 0; c < 5; ++c) {
    char* bufc = (c & 1) ? XsB : XsA;
    char* bufn = (c & 1) ? XsA : XsB;
    if (c < 4) LOADC(c + 1);
    P0_HALF(bufc, c, 0);
    if (c < 4) WRITEPX0(bufn);
    P0_HALF(bufc, c, 4);
    if (c < 4) WRITEPX1(bufn);
    __syncthreads();
  }

  // Y0 store overlays X buffers (barrier above guarantees all reads done)
  store_act32<2, 2>(acc0, sc, sh, w * 64, 0, lane, Y0s, 1024);
  __syncthreads();

  // ---- phase 1: 512 -> 256  (wave w: rows w*32..+31, both 32-px tiles), ring depth 8
  {
    f32x16 acc1[1][2] = {};
    const u16* A = Wb + 327680 + (size_t)w * (32 * 512) + lane * 8;
    bf16x8 ar8[8];
    #pragma unroll
    for (int q = 0; q < 8; ++q) ar8[q] = *reinterpret_cast<const bf16x8*>(A + q * 512);
    __builtin_amdgcn_s_setprio(1);
    #pragma unroll
    for (int ks = 0; ks < 32; ++ks) {
      const unsigned kb = (unsigned)(ks * 32 + khalf * 16);
      bf16x8 bb0 = *reinterpret_cast<const bf16x8*>(reinterpret_cast<const char*>(Y0s) + (((unsigned)(l31 * 1024) + kb) ^ sw));
      bf16x8 bb1 = *reinterpret_cast<const bf16x8*>(reinterpret_cast<const char*>(Y0s) + (((unsigned)((l31 + 32) * 1024) + kb) ^ sw));
      acc1[0][0] = __builtin_amdgcn_mfma_f32_32x32x16_bf16(ar8[ks & 7], bb0, acc1[0][0], 0, 0, 0);
      acc1[0][1] = __builtin_amdgcn_mfma_f32_32x32x16_bf16(ar8[ks & 7], bb1, acc1[0][1], 0, 0, 0);
      if (ks < 24) ar8[ks & 7] = *reinterpret_cast<const bf16x8*>(A + (ks + 8) * 512);
    }
    __builtin_amdgcn_s_setprio(0);
    __syncthreads();   // all waves done reading Y0
    store_act32<1, 2>(acc1, sc + 512, sh + 512, w * 32, 0, lane, Y0s, 512);   // Y1 overlays Y0
    __syncthreads();
  }

  // ---- phase 2: 256 -> 128  (wave w: mt=w&3 rows, nt=w>>2 32-px tile), ring depth 8
  {
    f32x16 acc2[1][1] = {};
    const u16* A = Wb + 458752 + (size_t)(w & 3) * (16 * 512) + lane * 8;
    const int pxb = (w >> 2) * 32;
    bf16x8 ar8[8];
    #pragma unroll
    for (int q = 0; q < 8; ++q) ar8[q] = *reinterpret_cast<const bf16x8*>(A + q * 512);
    __builtin_amdgcn_s_setprio(1);
    #pragma unroll
    for (int ks = 0; ks < 16; ++ks) {
      const unsigned kb = (unsigned)(ks * 32 + khalf * 16);
      bf16x8 bb0 = *reinterpret_cast<const bf16x8*>(reinterpret_cast<const char*>(Y0s) + (((unsigned)((pxb + l31) * 512) + kb) ^ sw));
      acc2[0][0] = __builtin_amdgcn_mfma_f32_32x32x16_bf16(ar8[ks & 7], bb0, acc2[0][0], 0, 0, 0);
      if (ks < 8) ar8[ks & 7] = *reinterpret_cast<const bf16x8*>(A + (ks + 8) * 512);
    }
    __builtin_amdgcn_s_setprio(0);
    // Y2 -> [32K,48K) (disjoint from Y1 reads in [0,32K))
    store_act32<1, 1>(acc2, sc + 768, sh + 768, (w & 3) * 32, w >> 2, lane, smem + 16384, 256);
    __syncthreads();
  }

  // ---- phase 3: 128 -> 64  (16x16x32; wave w: mt=w&3, n-tiles 2*(w>>2)+{0,1})
  {
    const int r16 = lane & 15, g = lane >> 4;
    f32x4 acc3[2] = {};
    const u16* A = Wb + 491520 + (size_t)(w & 3) * (4 * 512) + lane * 8;
    bf16x8 a4[4];
    #pragma unroll
    for (int q = 0; q < 4; ++q) a4[q] = *reinterpret_cast<const bf16x8*>(A + q * 512);
    const int ntb = (w >> 2) * 2;
    __builtin_amdgcn_s_setprio(1);
    #pragma unroll
    for (int ks = 0; ks < 4; ++ks) {
      #pragma unroll
      for (int nt = 0; nt < 2; ++nt) {
        const int px = (ntb + nt) * 16 + r16;
        const unsigned byte = ((unsigned)(px * 256 + ks * 64 + g * 16)) ^ ((unsigned)((px & 7) << 4));
        bf16x8 bb = *reinterpret_cast<const bf16x8*>(reinterpret_cast<const char*>(smem) + 32768 + byte);
        acc3[nt] = __builtin_amdgcn_mfma_f32_16x16x32_bf16(a4[ks], bb, acc3[nt], 0, 0, 0);
      }
    }
    __builtin_amdgcn_s_setprio(0);
    const int c0 = (w & 3) * 16 + g * 4;
    const f32x4 s4 = *reinterpret_cast<const f32x4*>(sc + 896 + c0);
    const f32x4 h4 = *reinterpret_cast<const f32x4*>(sh + 896 + c0);
    u16* x3b = x3 + ((size_t)b << 21) + j0;
    #pragma unroll
    for (int nt = 0; nt < 2; ++nt) {
      const int n = (ntb + nt) * 16 + r16;
      #pragma unroll
      for (int r = 0; r < 4; ++r) {
        float vv2 = fmaxf(acc3[nt][r] * s4[r] + h4[r], 0.f);
        x3b[(size_t)(c0 + r) * 32768 + n] = f2bf(vv2);
      }
    }
  }
}

// ---------------- softmax over K + weighted sum with xyz (2 s per thread) ----------------
__global__ __launch_bounds__(256) void softmax_ws_kernel(
    const u16* __restrict__ x3, const float* __restrict__ xyz,
    float* __restrict__ out)
{
  const int tid = blockIdx.x * 256 + threadIdx.x;   // 0 .. 262143
  const int b = tid >> 15;
  const int rem = tid & 32767;
  const int d = rem >> 9;
  const int s0 = (rem & 511) * 2;

  const u16* xp = x3 + ((size_t)(b * 64 + d) << 15) + s0;
  float pa[32], pb[32];
  float mxa = -1e30f, mxb = -1e30f;
  #pragma unroll
  for (int k = 0; k < 32; ++k) {
    const unsigned u = *reinterpret_cast<const unsigned*>(xp + ((size_t)k << 10));
    const float va = bf2f((u16)(u & 0xFFFFu));
    const float vb = bf2f((u16)(u >> 16));
    pa[k] = va; pb[k] = vb;
    mxa = fmaxf(mxa, va); mxb = fmaxf(mxb, vb);
  }
  float sa = 0.f, sb = 0.f;
  #pragma unroll
  for (int k = 0; k < 32; ++k) {
    pa[k] = __expf(pa[k] - mxa); sa += pa[k];
    pb[k] = __expf(pb[k] - mxb); sb += pb[k];
  }
  const float inva = 1.0f / sa, invb = 1.0f / sb;

  const float* zp = xyz + (size_t)b * (3 * 32768) + s0;
  #pragma unroll
  for (int c = 0; c < 3; ++c) {
    float ax = 0.f, ay = 0.f;
    #pragma unroll
    for (int k = 0; k < 32; ++k) {
      const float2 z = *reinterpret_cast<const float2*>(zp + c * 32768 + (k << 10));
      ax += pa[k] * z.x; ay += pb[k] * z.y;
    }
    float2 o; o.x = ax * inva; o.y = ay * invb;
    *reinterpret_cast<float2*>(out + ((size_t)((b * 3 + c) * 64 + d) << 10) + s0) = o;
  }
}

// ---------------- launcher ----------------
extern "C" void kernel_launch(void* const* d_in, const int* in_sizes, int n_in,
                              void* d_out, int out_size, void* d_ws, size_t ws_size,
                              hipStream_t stream) {
  const float* xyz = (const float*)d_in[0];
  const float* gp  = (const float*)d_in[1];
  const float* W0 = (const float*)d_in[2];
  const float* W1 = (const float*)d_in[8];
  const float* W2 = (const float*)d_in[14];
  const float* W3 = (const float*)d_in[20];

  char* ws = (char*)d_ws;
  u16*   Wb = (u16*)ws;                       // 499712 bf16 -> 999424 B
  float* sc = (float*)(ws + 999424);          // 960 f32
  float* sh = (float*)(ws + 1003264);         // 960 f32
  u16*   x3 = (u16*)(ws + 1007104);           // 8*64*32768 bf16 = 33.5 MB

  prep_kernel<<<245, 256, 0, stream>>>(
      W0, W1, W2, W3,
      (const float*)d_in[3],  (const float*)d_in[4],  (const float*)d_in[5],  (const float*)d_in[6],  (const float*)d_in[7],
      (const float*)d_in[9],  (const float*)d_in[10], (const float*)d_in[11], (const float*)d_in[12], (const float*)d_in[13],
      (const float*)d_in[15], (const float*)d_in[16], (const float*)d_in[17], (const float*)d_in[18], (const float*)d_in[19],
      (const float*)d_in[21], (const float*)d_in[22], (const float*)d_in[23], (const float*)d_in[24], (const float*)d_in[25],
      Wb, sc, sh);

  fused4_kernel<<<4096, 512, 0, stream>>>(gp, Wb, sc, sh, x3);

  softmax_ws_kernel<<<1024, 256, 0, stream>>>(x3, xyz, (float*)d_out);
}